// Round 1
// baseline (122.346 us; speedup 1.0000x reference)
//
#include <hip/hip_runtime.h>
#include <math.h>

#define BB 32
#define SS 4
#define TT 4000
#define FF 96
#define FRAMES (BB * TT)   // 128000

// ws layout: [0] double ssum ; then 3x uint32 counters (correct, FA, MS)
struct WsLayout {
    double ssum;                  // offset 0
    unsigned int cnt[3];          // offset 8
};

__global__ __launch_bounds__(256) void frame_kernel(
    const float* __restrict__ x, const float* __restrict__ labels,
    const float* __restrict__ W, const float* __restrict__ bias,
    double* __restrict__ ssum_acc, unsigned int* __restrict__ cnt_acc)
{
    const int tid = threadIdx.x;
    const int sub = tid & 31;       // lane within 32-lane frame group
    const int s   = sub >> 3;       // 0..3  (the S dimension)
    const int l8  = sub & 7;        // lane within 8-lane row group
    const int g   = tid >> 5;       // frame-group within block (0..7)
    const int groups_per_block = blockDim.x >> 5;
    const int group_global = blockIdx.x * groups_per_block + g;
    const int group_stride = gridDim.x * groups_per_block;

    // Each lane owns features [l8*12, l8*12+12) of the 96-float row.
    const float4* W4 = reinterpret_cast<const float4*>(W);
    const float4 w0 = W4[l8 * 3 + 0];
    const float4 w1 = W4[l8 * 3 + 1];
    const float4 w2 = W4[l8 * 3 + 2];
    const float bval = bias[0];

    float bsum = 0.0f;
    unsigned int c_corr = 0, c_fa = 0, c_ms = 0;

    for (int frame = group_global; frame < FRAMES; frame += group_stride) {
        const int b = frame / TT;
        const int t = frame - b * TT;
        const long long row = ((long long)(b * SS + s)) * TT + t;

        const float4* xr = reinterpret_cast<const float4*>(x + row * FF) + l8 * 3;
        const float4 x0 = xr[0];
        const float4 x1 = xr[1];
        const float4 x2 = xr[2];

        float p = x0.x * w0.x + x0.y * w0.y + x0.z * w0.z + x0.w * w0.w
                + x1.x * w1.x + x1.y * w1.y + x1.z * w1.z + x1.w * w1.w
                + x2.x * w2.x + x2.y * w2.y + x2.z * w2.z + x2.w * w2.w;

        // 8-lane butterfly: all 8 lanes end with the full row dot-product
        p += __shfl_xor(p, 1);
        p += __shfl_xor(p, 2);
        p += __shfl_xor(p, 4);

        const float logit = p + bval;
        const float lab = labels[row];          // same addr across the 8 lanes (broadcast)
        const int pred = (logit > 0.0f) ? 1 : 0;

        // stable softplus: max(z,0) + log1p(exp(-|z|))  (== jax.nn.softplus)
        const float sp = fmaxf(logit, 0.0f) + log1pf(expf(-fabsf(logit)));
        const float bce = sp - logit * lab;
        if (l8 == 0) bsum += bce;

        const int eq = ((pred ? 1.0f : 0.0f) == lab) ? 1 : 0;
        const int lz = (lab == 0.0f) ? 1 : 0;
        const int pz = pred ? 0 : 1;
        int f = eq | (lz << 1) | (pz << 2);
        // AND-combine the 4 s-rows of this frame (lanes s*8.. within the 32-half)
        f &= __shfl_xor(f, 8);
        f &= __shfl_xor(f, 16);

        if (sub == 0) {
            const int match = f & 1;
            const int flz = (f >> 1) & 1;
            const int fpz = (f >> 2) & 1;
            c_corr += match;
            c_fa   += (!match) & flz;
            c_ms   += (!match) & (!flz) & fpz;
        }
    }

    // wave-wide butterfly reduce (64 lanes)
    int ic = (int)c_corr, ifa = (int)c_fa, ims = (int)c_ms;
    for (int m = 1; m < 64; m <<= 1) {
        bsum += __shfl_xor(bsum, m);
        ic   += __shfl_xor(ic, m);
        ifa  += __shfl_xor(ifa, m);
        ims  += __shfl_xor(ims, m);
    }

    __shared__ double s_sum[4];
    __shared__ int s_c[4][3];
    const int wave = tid >> 6;
    if ((tid & 63) == 0) {
        s_sum[wave] = (double)bsum;
        s_c[wave][0] = ic; s_c[wave][1] = ifa; s_c[wave][2] = ims;
    }
    __syncthreads();
    if (tid == 0) {
        double tot = 0.0;
        int tc = 0, tf = 0, tm = 0;
        const int nw = blockDim.x >> 6;
        for (int w = 0; w < nw; ++w) {
            tot += s_sum[w];
            tc += s_c[w][0]; tf += s_c[w][1]; tm += s_c[w][2];
        }
        atomicAdd(ssum_acc, tot);
        atomicAdd(cnt_acc + 0, (unsigned int)tc);
        atomicAdd(cnt_acc + 1, (unsigned int)tf);
        atomicAdd(cnt_acc + 2, (unsigned int)tm);
    }
}

__global__ void finalize_kernel(const double* __restrict__ ssum_acc,
                                const unsigned int* __restrict__ cnt_acc,
                                float* __restrict__ out)
{
    if (threadIdx.x != 0 || blockIdx.x != 0) return;
    const double Ssum = ssum_acc[0];
    const double BT = (double)FRAMES;

    const double total_loss = Ssum / BT + Ssum / 4.0;
    const double loss = total_loss / BT;

    double C  = (double)cnt_acc[0];
    double FA = (double)cnt_acc[1];
    double MS = (double)cnt_acc[2];
    double SC = BT - C - FA - MS;

    // replicate the reference's sequential normalization order exactly
    const double d0 = MS + FA + SC + C;
    const double DER = (MS + FA + SC) / d0;
    MS = MS / d0;
    const double d1 = MS + FA + SC + C;
    FA = FA / d1;
    const double d2 = MS + FA + SC + C;
    SC = SC / d2;

    out[0] = (float)loss;
    out[1] = (float)DER;
    out[2] = (float)MS;
    out[3] = (float)FA;
    out[4] = (float)SC;
}

extern "C" void kernel_launch(void* const* d_in, const int* in_sizes, int n_in,
                              void* d_out, int out_size, void* d_ws, size_t ws_size,
                              hipStream_t stream) {
    const float* x      = (const float*)d_in[0];
    const float* labels = (const float*)d_in[1];
    const float* W      = (const float*)d_in[2];
    const float* bias   = (const float*)d_in[3];
    float* out = (float*)d_out;

    double* ssum_acc = (double*)d_ws;
    unsigned int* cnt_acc = (unsigned int*)((char*)d_ws + 8);

    // zero the accumulators every call (d_ws is NOT re-poisoned between replays)
    hipMemsetAsync(d_ws, 0, 32, stream);

    const int blocks = 2000;   // 8 frame-groups/block -> 16000 groups, 8 iters each
    frame_kernel<<<blocks, 256, 0, stream>>>(x, labels, W, bias, ssum_acc, cnt_acc);
    finalize_kernel<<<1, 1, 0, stream>>>(ssum_acc, cnt_acc, out);
}

// Round 2
// 117.706 us; speedup vs baseline: 1.0394x; 1.0394x over previous
//
#include <hip/hip_runtime.h>
#include <math.h>

#define BB 32
#define SS 4
#define TT 4000
#define FF 96
#define FRAMES (BB * TT)        // 128000
#define GROUPS 16000            // frames / 8
#define FPG 8                   // frames per 32-lane group (8 | 4000, so no b-crossing)

__global__ __launch_bounds__(256) void frame_kernel(
    const float* __restrict__ x, const float* __restrict__ labels,
    const float* __restrict__ W, const float* __restrict__ bias,
    double* __restrict__ ssum_acc, unsigned int* __restrict__ cnt_acc)
{
    const int tid = threadIdx.x;
    const int sub = tid & 31;       // lane within 32-lane frame group
    const int s   = sub >> 3;       // 0..3  (the S dimension)
    const int l8  = sub & 7;        // lane within 8-lane row group
    const int g   = tid >> 5;       // frame-group within block (0..7)
    const unsigned int group = blockIdx.x * 8u + (unsigned int)g;   // 0..15999

    // chunked frame assignment: group owns frames [group*8, group*8+8)
    // 4000 frames per b, 8 | 4000 -> chunk stays within one b
    const unsigned int b  = group / 500u;                 // magic-mul, no real div
    const unsigned int t0 = (group - b * 500u) * FPG;

    // lane owns features {l8*4..+4} of each 32-float third: W4[l8 + 8k]
    const float4* W4 = reinterpret_cast<const float4*>(W);
    const float4 w0 = W4[l8];
    const float4 w1 = W4[l8 + 8];
    const float4 w2 = W4[l8 + 16];
    const float bval = bias[0];

    const unsigned int rowb = (b * 4u + (unsigned int)s) * (unsigned int)TT + t0;
    const float4* xb = reinterpret_cast<const float4*>(x) + (size_t)rowb * 24 + l8;
    const float* labp = labels + rowb;

    float bsum = 0.0f;          // each row's bce added by all 8 lanes -> scale 1/8 later
    int c_corr = 0, c_fa = 0, c_ms = 0;   // each frame counted by all 32 lanes -> >>5 later

    #pragma unroll
    for (int half = 0; half < 2; ++half) {
        float4 xv[4][3];
        float  labv[4];
        // issue all 16 loads of this batch before consuming any
        #pragma unroll
        for (int u = 0; u < 4; ++u) {
            const int j = half * 4 + u;
            const float4* xr = xb + j * 24;     // row-major: 24 float4 per row
            xv[u][0] = xr[0];                   // 128B contiguous per 8-lane group
            xv[u][1] = xr[8];
            xv[u][2] = xr[16];
            labv[u]  = labp[j];
        }
        #pragma unroll
        for (int u = 0; u < 4; ++u) {
            float p = xv[u][0].x * w0.x + xv[u][0].y * w0.y + xv[u][0].z * w0.z + xv[u][0].w * w0.w
                    + xv[u][1].x * w1.x + xv[u][1].y * w1.y + xv[u][1].z * w1.z + xv[u][1].w * w1.w
                    + xv[u][2].x * w2.x + xv[u][2].y * w2.y + xv[u][2].z * w2.z + xv[u][2].w * w2.w;
            // 8-lane butterfly: all 8 lanes end with the full row dot-product
            p += __shfl_xor(p, 1);
            p += __shfl_xor(p, 2);
            p += __shfl_xor(p, 4);

            const float logit = p + bval;
            const float lab = labv[u];
            const int pred = (logit > 0.0f) ? 1 : 0;

            // stable softplus: max(z,0) + log1p(exp(-|z|))
            const float sp = fmaxf(logit, 0.0f) + log1pf(expf(-fabsf(logit)));
            bsum += sp - logit * lab;           // all 8 lanes add same value (x8)

            const int eq = ((pred ? 1.0f : 0.0f) == lab) ? 1 : 0;
            const int lz = (lab == 0.0f) ? 1 : 0;
            const int pz = pred ? 0 : 1;
            int f = eq | (lz << 1) | (pz << 2);
            // AND-combine the 4 s-rows of this frame
            f &= __shfl_xor(f, 8);
            f &= __shfl_xor(f, 16);

            const int match = f & 1;
            const int flz = (f >> 1) & 1;
            const int fpz = (f >> 2) & 1;
            c_corr += match;                            // all 32 lanes add (x32)
            c_fa   += (!match) & flz;
            c_ms   += (!match) & (!flz) & fpz;
        }
    }

    // wave-wide butterfly reduce (64 lanes)
    int ic = c_corr, ifa = c_fa, ims = c_ms;
    for (int m = 1; m < 64; m <<= 1) {
        bsum += __shfl_xor(bsum, m);
        ic   += __shfl_xor(ic, m);
        ifa  += __shfl_xor(ifa, m);
        ims  += __shfl_xor(ims, m);
    }

    __shared__ double s_sum[4];
    __shared__ int s_c[4][3];
    const int wave = tid >> 6;
    if ((tid & 63) == 0) {
        s_sum[wave] = (double)bsum;
        s_c[wave][0] = ic; s_c[wave][1] = ifa; s_c[wave][2] = ims;
    }
    __syncthreads();
    if (tid == 0) {
        double tot = 0.0;
        int tc = 0, tf = 0, tm = 0;
        for (int w = 0; w < 4; ++w) {
            tot += s_sum[w];
            tc += s_c[w][0]; tf += s_c[w][1]; tm += s_c[w][2];
        }
        atomicAdd(ssum_acc, tot * 0.125);               // undo x8 bce replication
        atomicAdd(cnt_acc + 0, (unsigned int)(tc >> 5)); // undo x32 count replication
        atomicAdd(cnt_acc + 1, (unsigned int)(tf >> 5));
        atomicAdd(cnt_acc + 2, (unsigned int)(tm >> 5));
    }
}

__global__ void finalize_kernel(const double* __restrict__ ssum_acc,
                                const unsigned int* __restrict__ cnt_acc,
                                float* __restrict__ out)
{
    if (threadIdx.x != 0 || blockIdx.x != 0) return;
    const double Ssum = ssum_acc[0];
    const double BT = (double)FRAMES;

    const double total_loss = Ssum / BT + Ssum / 4.0;
    const double loss = total_loss / BT;

    double C  = (double)cnt_acc[0];
    double FA = (double)cnt_acc[1];
    double MS = (double)cnt_acc[2];
    double SC = BT - C - FA - MS;

    // replicate the reference's sequential normalization order exactly
    const double d0 = MS + FA + SC + C;
    const double DER = (MS + FA + SC) / d0;
    MS = MS / d0;
    const double d1 = MS + FA + SC + C;
    FA = FA / d1;
    const double d2 = MS + FA + SC + C;
    SC = SC / d2;

    out[0] = (float)loss;
    out[1] = (float)DER;
    out[2] = (float)MS;
    out[3] = (float)FA;
    out[4] = (float)SC;
}

extern "C" void kernel_launch(void* const* d_in, const int* in_sizes, int n_in,
                              void* d_out, int out_size, void* d_ws, size_t ws_size,
                              hipStream_t stream) {
    const float* x      = (const float*)d_in[0];
    const float* labels = (const float*)d_in[1];
    const float* W      = (const float*)d_in[2];
    const float* bias   = (const float*)d_in[3];
    float* out = (float*)d_out;

    double* ssum_acc = (double*)d_ws;
    unsigned int* cnt_acc = (unsigned int*)((char*)d_ws + 8);

    hipMemsetAsync(d_ws, 0, 32, stream);

    frame_kernel<<<GROUPS / 8, 256, 0, stream>>>(x, labels, W, bias, ssum_acc, cnt_acc);
    finalize_kernel<<<1, 1, 0, stream>>>(ssum_acc, cnt_acc, out);
}

// Round 3
// 117.125 us; speedup vs baseline: 1.0446x; 1.0050x over previous
//
#include <hip/hip_runtime.h>
#include <math.h>

#define BB 32
#define SS 4
#define TT 4000
#define FF 96
#define FRAMES (BB * TT)        // 128000
#define GROUPS 16000            // frames / 8
#define FPG 8                   // frames per 32-lane group (8 | 4000, so no b-crossing)

__global__ __launch_bounds__(256) void frame_kernel(
    const float* __restrict__ x, const float* __restrict__ labels,
    const float* __restrict__ W, const float* __restrict__ bias,
    double* __restrict__ ssum_acc, unsigned int* __restrict__ cnt_acc)
{
    const int tid = threadIdx.x;
    const int sub = tid & 31;       // lane within 32-lane frame group
    const int s   = sub >> 3;       // 0..3  (the S dimension)
    const int l8  = sub & 7;        // lane within 8-lane row group
    const int g   = tid >> 5;       // frame-group within block (0..7)
    const unsigned int group = blockIdx.x * 8u + (unsigned int)g;   // 0..15999

    // group owns frames [group*8, group*8+8); 8 | 4000 so chunk stays in one b
    const unsigned int b  = group / 500u;
    const unsigned int t0 = (group - b * 500u) * FPG;

    const float4* W4 = reinterpret_cast<const float4*>(W);
    const float4 w0 = W4[l8];
    const float4 w1 = W4[l8 + 8];
    const float4 w2 = W4[l8 + 16];
    const float bval = bias[0];

    const unsigned int rowb = (b * 4u + (unsigned int)s) * (unsigned int)TT + t0;
    const float4* xb = reinterpret_cast<const float4*>(x) + (size_t)rowb * 24 + l8;

    // ---- load phase: 26 independent loads, all issued before any use ----
    // labels: rowb is a multiple of 8 -> 32B aligned -> two float4 loads
    const float4* lp4 = reinterpret_cast<const float4*>(labels + rowb);
    const float4 labA = lp4[0];     // frames 0..3
    const float4 labB = lp4[1];     // frames 4..7

    float4 xq[FPG][3];
    #pragma unroll
    for (int j = 0; j < FPG; ++j) {
        const float4* xr = xb + j * 24;   // 24 float4 per row
        xq[j][0] = xr[0];                 // each: 128B contiguous per 8-lane group
        xq[j][1] = xr[8];
        xq[j][2] = xr[16];
    }
    // forbid the scheduler from sinking loads into the compute phase
    __builtin_amdgcn_sched_barrier(0);

    // ---- compute phase ----
    float bsum = 0.0f;                    // x8 replicated (all 8 lanes)
    int c_corr = 0, c_fa = 0, c_ms = 0;   // x32 replicated (all 32 lanes)

    const float labarr[8] = {labA.x, labA.y, labA.z, labA.w,
                             labB.x, labB.y, labB.z, labB.w};

    #pragma unroll
    for (int j = 0; j < FPG; ++j) {
        float p = xq[j][0].x * w0.x + xq[j][0].y * w0.y + xq[j][0].z * w0.z + xq[j][0].w * w0.w
                + xq[j][1].x * w1.x + xq[j][1].y * w1.y + xq[j][1].z * w1.z + xq[j][1].w * w1.w
                + xq[j][2].x * w2.x + xq[j][2].y * w2.y + xq[j][2].z * w2.z + xq[j][2].w * w2.w;
        p += __shfl_xor(p, 1);
        p += __shfl_xor(p, 2);
        p += __shfl_xor(p, 4);

        const float logit = p + bval;
        const float lab = labarr[j];
        const int pred = (logit > 0.0f) ? 1 : 0;

        // stable softplus: max(z,0) + log1p(exp(-|z|))
        const float sp = fmaxf(logit, 0.0f) + log1pf(expf(-fabsf(logit)));
        bsum += sp - logit * lab;

        const int eq = ((pred ? 1.0f : 0.0f) == lab) ? 1 : 0;
        const int lz = (lab == 0.0f) ? 1 : 0;
        const int pz = pred ? 0 : 1;
        int f = eq | (lz << 1) | (pz << 2);
        f &= __shfl_xor(f, 8);
        f &= __shfl_xor(f, 16);

        const int match = f & 1;
        const int flz = (f >> 1) & 1;
        const int fpz = (f >> 2) & 1;
        c_corr += match;
        c_fa   += (!match) & flz;
        c_ms   += (!match) & (!flz) & fpz;
    }

    // wave-wide butterfly reduce (64 lanes)
    int ic = c_corr, ifa = c_fa, ims = c_ms;
    for (int m = 1; m < 64; m <<= 1) {
        bsum += __shfl_xor(bsum, m);
        ic   += __shfl_xor(ic, m);
        ifa  += __shfl_xor(ifa, m);
        ims  += __shfl_xor(ims, m);
    }

    __shared__ double s_sum[4];
    __shared__ int s_c[4][3];
    const int wave = tid >> 6;
    if ((tid & 63) == 0) {
        s_sum[wave] = (double)bsum;
        s_c[wave][0] = ic; s_c[wave][1] = ifa; s_c[wave][2] = ims;
    }
    __syncthreads();
    if (tid == 0) {
        double tot = 0.0;
        int tc = 0, tf = 0, tm = 0;
        for (int w = 0; w < 4; ++w) {
            tot += s_sum[w];
            tc += s_c[w][0]; tf += s_c[w][1]; tm += s_c[w][2];
        }
        atomicAdd(ssum_acc, tot * 0.125);                // undo x8 bce replication
        atomicAdd(cnt_acc + 0, (unsigned int)(tc >> 5)); // undo x32 replication
        atomicAdd(cnt_acc + 1, (unsigned int)(tf >> 5));
        atomicAdd(cnt_acc + 2, (unsigned int)(tm >> 5));
    }
}

__global__ void finalize_kernel(const double* __restrict__ ssum_acc,
                                const unsigned int* __restrict__ cnt_acc,
                                float* __restrict__ out)
{
    if (threadIdx.x != 0 || blockIdx.x != 0) return;
    const double Ssum = ssum_acc[0];
    const double BT = (double)FRAMES;

    const double total_loss = Ssum / BT + Ssum / 4.0;
    const double loss = total_loss / BT;

    double C  = (double)cnt_acc[0];
    double FA = (double)cnt_acc[1];
    double MS = (double)cnt_acc[2];
    double SC = BT - C - FA - MS;

    const double d0 = MS + FA + SC + C;
    const double DER = (MS + FA + SC) / d0;
    MS = MS / d0;
    const double d1 = MS + FA + SC + C;
    FA = FA / d1;
    const double d2 = MS + FA + SC + C;
    SC = SC / d2;

    out[0] = (float)loss;
    out[1] = (float)DER;
    out[2] = (float)MS;
    out[3] = (float)FA;
    out[4] = (float)SC;
}

extern "C" void kernel_launch(void* const* d_in, const int* in_sizes, int n_in,
                              void* d_out, int out_size, void* d_ws, size_t ws_size,
                              hipStream_t stream) {
    const float* x      = (const float*)d_in[0];
    const float* labels = (const float*)d_in[1];
    const float* W      = (const float*)d_in[2];
    const float* bias   = (const float*)d_in[3];
    float* out = (float*)d_out;

    double* ssum_acc = (double*)d_ws;
    unsigned int* cnt_acc = (unsigned int*)((char*)d_ws + 8);

    hipMemsetAsync(d_ws, 0, 32, stream);

    frame_kernel<<<GROUPS / 8, 256, 0, stream>>>(x, labels, W, bias, ssum_acc, cnt_acc);
    finalize_kernel<<<1, 1, 0, stream>>>(ssum_acc, cnt_acc, out);
}

// Round 4
// 43.841 us; speedup vs baseline: 2.7906x; 2.6716x over previous
//
#include <hip/hip_runtime.h>
#include <math.h>

#define BB 32
#define SS 4
#define TT 4000
#define FF 96
#define FRAMES (BB * TT)        // 128000
#define GROUPS 16000            // frames / 8
#define FPG 8                   // frames per 32-lane group (8 | 4000, so no b-crossing)
#define NBLOCKS (GROUPS / 8)    // 2000

// ws layout: double psum[NBLOCKS] @ 0 ; uint4 pcnt[NBLOCKS] @ 16000B
__global__ __launch_bounds__(256) void frame_kernel(
    const float* __restrict__ x, const float* __restrict__ labels,
    const float* __restrict__ W, const float* __restrict__ bias,
    double* __restrict__ psum, uint4* __restrict__ pcnt)
{
    const int tid = threadIdx.x;
    const int sub = tid & 31;       // lane within 32-lane frame group
    const int s   = sub >> 3;       // 0..3  (the S dimension)
    const int l8  = sub & 7;        // lane within 8-lane row group
    const int g   = tid >> 5;       // frame-group within block (0..7)
    const unsigned int group = blockIdx.x * 8u + (unsigned int)g;   // 0..15999

    // group owns frames [group*8, group*8+8); 8 | 4000 so chunk stays in one b
    const unsigned int b  = group / 500u;
    const unsigned int t0 = (group - b * 500u) * FPG;

    const float4* W4 = reinterpret_cast<const float4*>(W);
    const float4 w0 = W4[l8];
    const float4 w1 = W4[l8 + 8];
    const float4 w2 = W4[l8 + 16];
    const float bval = bias[0];

    const unsigned int rowb = (b * 4u + (unsigned int)s) * (unsigned int)TT + t0;
    const float4* xb = reinterpret_cast<const float4*>(x) + (size_t)rowb * 24 + l8;

    // labels: rowb multiple of 8 -> 32B aligned -> two float4 loads
    const float4* lp4 = reinterpret_cast<const float4*>(labels + rowb);
    const float4 labA = lp4[0];
    const float4 labB = lp4[1];
    const float labarr[8] = {labA.x, labA.y, labA.z, labA.w,
                             labB.x, labB.y, labB.z, labB.w};

    float bsum = 0.0f;                    // x8 replicated (all 8 lanes)
    int c_corr = 0, c_fa = 0, c_ms = 0;   // x32 replicated (all 32 lanes)

    #pragma unroll
    for (int half = 0; half < 2; ++half) {
        float4 xv[4][3];
        #pragma unroll
        for (int u = 0; u < 4; ++u) {
            const int j = half * 4 + u;
            const float4* xr = xb + j * 24;
            xv[u][0] = xr[0];
            xv[u][1] = xr[8];
            xv[u][2] = xr[16];
        }
        #pragma unroll
        for (int u = 0; u < 4; ++u) {
            const int j = half * 4 + u;
            float p = xv[u][0].x * w0.x + xv[u][0].y * w0.y + xv[u][0].z * w0.z + xv[u][0].w * w0.w
                    + xv[u][1].x * w1.x + xv[u][1].y * w1.y + xv[u][1].z * w1.z + xv[u][1].w * w1.w
                    + xv[u][2].x * w2.x + xv[u][2].y * w2.y + xv[u][2].z * w2.z + xv[u][2].w * w2.w;
            p += __shfl_xor(p, 1);
            p += __shfl_xor(p, 2);
            p += __shfl_xor(p, 4);

            const float logit = p + bval;
            const float lab = labarr[j];
            const int pred = (logit > 0.0f) ? 1 : 0;

            // stable softplus: max(z,0) + log1p(exp(-|z|))
            const float sp = fmaxf(logit, 0.0f) + log1pf(expf(-fabsf(logit)));
            bsum += sp - logit * lab;

            const int eq = ((pred ? 1.0f : 0.0f) == lab) ? 1 : 0;
            const int lz = (lab == 0.0f) ? 1 : 0;
            const int pz = pred ? 0 : 1;
            int f = eq | (lz << 1) | (pz << 2);
            f &= __shfl_xor(f, 8);
            f &= __shfl_xor(f, 16);

            const int match = f & 1;
            const int flz = (f >> 1) & 1;
            const int fpz = (f >> 2) & 1;
            c_corr += match;
            c_fa   += (!match) & flz;
            c_ms   += (!match) & (!flz) & fpz;
        }
    }

    // wave-wide butterfly reduce (64 lanes)
    int ic = c_corr, ifa = c_fa, ims = c_ms;
    for (int m = 1; m < 64; m <<= 1) {
        bsum += __shfl_xor(bsum, m);
        ic   += __shfl_xor(ic, m);
        ifa  += __shfl_xor(ifa, m);
        ims  += __shfl_xor(ims, m);
    }

    __shared__ double s_sum[4];
    __shared__ int s_c[4][3];
    const int wave = tid >> 6;
    if ((tid & 63) == 0) {
        s_sum[wave] = (double)bsum;
        s_c[wave][0] = ic; s_c[wave][1] = ifa; s_c[wave][2] = ims;
    }
    __syncthreads();
    if (tid == 0) {
        double tot = 0.0;
        int tc = 0, tf = 0, tm = 0;
        for (int w = 0; w < 4; ++w) {
            tot += s_sum[w];
            tc += s_c[w][0]; tf += s_c[w][1]; tm += s_c[w][2];
        }
        // NO atomics: each block writes its own slot (plain stores, no contention)
        psum[blockIdx.x] = tot * 0.125;               // undo x8 bce replication
        pcnt[blockIdx.x] = make_uint4((unsigned int)(tc >> 5),
                                      (unsigned int)(tf >> 5),
                                      (unsigned int)(tm >> 5), 0u);
    }
}

__global__ __launch_bounds__(256) void finalize_kernel(
    const double* __restrict__ psum, const uint4* __restrict__ pcnt,
    float* __restrict__ out)
{
    const int tid = threadIdx.x;

    double sum = 0.0;
    int tc = 0, tf = 0, tm = 0;
    for (int i = tid; i < NBLOCKS; i += 256) {
        sum += psum[i];
        const uint4 c = pcnt[i];
        tc += (int)c.x; tf += (int)c.y; tm += (int)c.z;
    }
    // 64-lane butterfly
    for (int m = 1; m < 64; m <<= 1) {
        sum += __shfl_xor(sum, m);
        tc  += __shfl_xor(tc, m);
        tf  += __shfl_xor(tf, m);
        tm  += __shfl_xor(tm, m);
    }
    __shared__ double s_sum[4];
    __shared__ int s_c[4][3];
    const int wave = tid >> 6;
    if ((tid & 63) == 0) {
        s_sum[wave] = sum;
        s_c[wave][0] = tc; s_c[wave][1] = tf; s_c[wave][2] = tm;
    }
    __syncthreads();
    if (tid != 0) return;

    double Ssum = 0.0;
    int C_i = 0, FA_i = 0, MS_i = 0;
    for (int w = 0; w < 4; ++w) {
        Ssum += s_sum[w];
        C_i += s_c[w][0]; FA_i += s_c[w][1]; MS_i += s_c[w][2];
    }

    const double BT = (double)FRAMES;
    const double total_loss = Ssum / BT + Ssum / 4.0;
    const double loss = total_loss / BT;

    double C  = (double)C_i;
    double FA = (double)FA_i;
    double MS = (double)MS_i;
    double SC = BT - C - FA - MS;

    // replicate the reference's sequential normalization order exactly
    const double d0 = MS + FA + SC + C;
    const double DER = (MS + FA + SC) / d0;
    MS = MS / d0;
    const double d1 = MS + FA + SC + C;
    FA = FA / d1;
    const double d2 = MS + FA + SC + C;
    SC = SC / d2;

    out[0] = (float)loss;
    out[1] = (float)DER;
    out[2] = (float)MS;
    out[3] = (float)FA;
    out[4] = (float)SC;
}

extern "C" void kernel_launch(void* const* d_in, const int* in_sizes, int n_in,
                              void* d_out, int out_size, void* d_ws, size_t ws_size,
                              hipStream_t stream) {
    const float* x      = (const float*)d_in[0];
    const float* labels = (const float*)d_in[1];
    const float* W      = (const float*)d_in[2];
    const float* bias   = (const float*)d_in[3];
    float* out = (float*)d_out;

    double* psum = (double*)d_ws;                               // 16000 B
    uint4*  pcnt = (uint4*)((char*)d_ws + NBLOCKS * sizeof(double)); // 32000 B

    // no memset needed: every partial slot is written unconditionally each call

    frame_kernel<<<NBLOCKS, 256, 0, stream>>>(x, labels, W, bias, psum, pcnt);
    finalize_kernel<<<1, 256, 0, stream>>>(psum, pcnt, out);
}